// Round 1
// baseline (639.148 us; speedup 1.0000x reference)
//
#include <hip/hip_runtime.h>
#include <math.h>

#define WE 300
#define DEp 256
#define VV 50000
#define DDim 100000
#define BB 4096
#define NGc 10

__device__ __forceinline__ float wave_reduce(float v) {
    #pragma unroll
    for (int o = 32; o > 0; o >>= 1) v += __shfl_down(v, o, 64);
    return v;
}

// log(sigmoid(x)), numerically stable
__device__ __forceinline__ float logsigf(float x) {
    return (x >= 0.f) ? -log1pf(expf(-x)) : x - log1pf(expf(x));
}

__global__ void k_init(double* p, int n) {
    int i = blockIdx.x * blockDim.x + threadIdx.x;
    if (i < n) p[i] = 0.0;
}

// One block per b (320 threads, 300 active): gather g column, normalize, store normed[b][w]
__global__ __launch_bounds__(320) void k_gather(const float* __restrict__ rv,
                                                const int* __restrict__ wid,
                                                float* __restrict__ normed) {
    int b = blockIdx.x;
    int tid = threadIdx.x;
    __shared__ int ids[NGc];
    __shared__ float wpart[5];
    __shared__ float s_inv;
    if (tid < NGc) ids[tid] = wid[b * NGc + tid];
    __syncthreads();
    float g = 0.f;
    if (tid < WE) {
        const float* row = rv + (size_t)tid * VV;
        #pragma unroll
        for (int ng = 0; ng < NGc; ++ng) g += row[ids[ng]];
        g *= 0.1f;
    }
    float r = wave_reduce(g * g);
    int lane = tid & 63, wv = tid >> 6;
    if (lane == 0) wpart[wv] = r;
    __syncthreads();
    if (tid == 0) {
        float s = wpart[0] + wpart[1] + wpart[2] + wpart[3] + wpart[4];
        s_inv = 1.0f / sqrtf(s);
    }
    __syncthreads();
    if (tid < WE) normed[(size_t)b * WE + tid] = g * s_inv;
}

// t_pre[b][de] = sum_w proj[de][w] * normed[b][w].  M=256(de) x N=4096(b) x K=300.
// 64x64 tiles, 256 threads, 4x4 micro-tile. Output stored b-major: tpre[b*256+de].
__global__ __launch_bounds__(256) void k_gemm(const float* __restrict__ proj,
                                              const float* __restrict__ normed,
                                              float* __restrict__ tpre) {
    __shared__ float As[64 * 33];   // proj tile  [de][k], pad 33 (2-way conflicts are free)
    __shared__ float Bs[64 * 33];   // normed tile [b][k]
    int tid = threadIdx.x;
    int tx = tid & 15, ty = tid >> 4;   // tx -> de micro, ty -> b micro
    int de0 = blockIdx.y * 64;
    int b0  = blockIdx.x * 64;
    float acc[4][4] = {};
    int f = tid & 7, r0 = tid >> 3;     // f: float4 within 32-wide k chunk; r0: row 0..31
    for (int kt = 0; kt < 10; ++kt) {
        int k0 = kt * 32;
        __syncthreads();
        for (int rr = r0; rr < 64; rr += 32) {
            int k = k0 + f * 4;
            float4 va = make_float4(0.f, 0.f, 0.f, 0.f);
            float4 vb = make_float4(0.f, 0.f, 0.f, 0.f);
            if (k + 3 < WE) {
                va = *(const float4*)(proj + (size_t)(de0 + rr) * WE + k);
                vb = *(const float4*)(normed + (size_t)(b0 + rr) * WE + k);
            }
            float* ap = &As[rr * 33 + f * 4];
            ap[0] = va.x; ap[1] = va.y; ap[2] = va.z; ap[3] = va.w;
            float* bp = &Bs[rr * 33 + f * 4];
            bp[0] = vb.x; bp[1] = vb.y; bp[2] = vb.z; bp[3] = vb.w;
        }
        __syncthreads();
        #pragma unroll
        for (int k = 0; k < 32; ++k) {
            float a[4], bv[4];
            #pragma unroll
            for (int i = 0; i < 4; ++i) a[i] = As[(tx * 4 + i) * 33 + k];
            #pragma unroll
            for (int j = 0; j < 4; ++j) bv[j] = Bs[(ty * 4 + j) * 33 + k];
            #pragma unroll
            for (int j = 0; j < 4; ++j)
                #pragma unroll
                for (int i = 0; i < 4; ++i) acc[j][i] += a[i] * bv[j];
        }
    }
    #pragma unroll
    for (int jb = 0; jb < 4; ++jb) {
        int b = b0 + ty * 4 + jb;
        float4 v = make_float4(acc[jb][0], acc[jb][1], acc[jb][2], acc[jb][3]);
        *(float4*)(tpre + (size_t)b * DEp + de0 + tx * 4) = v;
    }
}

// Partial row sums over b-chunks; coalesced reads of b-major tpre.
__global__ __launch_bounds__(256) void k_stats1(const float* __restrict__ tpre,
                                                double* __restrict__ rowsum,
                                                double* __restrict__ rowsq) {
    int de = threadIdx.x;
    int c0 = blockIdx.x * 64;
    float s = 0.f, ss = 0.f;
    for (int i = 0; i < 64; ++i) {
        float v = tpre[(size_t)(c0 + i) * DEp + de];
        s += v; ss += v * v;
    }
    atomicAdd(&rowsum[de], (double)s);
    atomicAdd(&rowsq[de], (double)ss);
}

__global__ void k_stats2(const double* __restrict__ rowsum, const double* __restrict__ rowsq,
                         float* __restrict__ meanf, float* __restrict__ scalef) {
    int de = threadIdx.x;
    double s = rowsum[de], ss = rowsq[de];
    double mean = s / (double)BB;
    double var = (ss - s * s / (double)BB) / (double)(BB - 1);
    double stdv = sqrt(var);
    meanf[de]  = (float)mean;
    scalef[de] = (float)(1.0 / sqrt(stdv));   // reference divides by sqrt(std) = var^0.25
}

// One block per b: build t column, dot with 1 doc + 10 neg rd columns, log terms, atomicAdd.
__global__ __launch_bounds__(256) void k_loss(const float* __restrict__ tpre,
                                              const float* __restrict__ meanf,
                                              const float* __restrict__ scalef,
                                              const float* __restrict__ beta,
                                              const float* __restrict__ rd,
                                              const int* __restrict__ doc_ids,
                                              const int* __restrict__ neg_ids,
                                              double* __restrict__ acc) {
    int b = blockIdx.x;
    int de = threadIdx.x;
    float t = tpre[(size_t)b * DEp + de];
    float tv = (t - meanf[de]) * scalef[de] + beta[de];
    tv = fminf(1.f, fmaxf(-1.f, tv));
    const float* rdrow = rd + (size_t)de * DDim;
    __shared__ int ids[11];
    if (de == 0) ids[0] = doc_ids[b];
    if (de >= 1 && de < 11) ids[de] = neg_ids[b * NGc + de - 1];
    __syncthreads();
    float prod[11];
    #pragma unroll
    for (int j = 0; j < 11; ++j) prod[j] = tv * rdrow[ids[j]];
    __shared__ float part[11][4];
    int lane = de & 63, wv = de >> 6;
    #pragma unroll
    for (int j = 0; j < 11; ++j) {
        float r = wave_reduce(prod[j]);
        if (lane == 0) part[j][wv] = r;
    }
    __syncthreads();
    if (de == 0) {
        float x0 = part[0][0] + part[0][1] + part[0][2] + part[0][3];
        // Z * log(min(sigmoid(x0), 0.999))
        float total = 10.f * fminf(logsigf(x0), -1.0005003e-3f);
        #pragma unroll
        for (int j = 1; j < 11; ++j) {
            float xj = part[j][0] + part[j][1] + part[j][2] + part[j][3];
            // log(max(sigmoid(-xj), 0.01))
            total += fmaxf(logsigf(-xj), -4.6051702f);
        }
        atomicAdd(acc, (double)(0.55f * total));   // (Z+1)/(2Z) = 0.55
    }
}

// Grid-stride sum of squares (float4), double atomic per block.
__global__ __launch_bounds__(256) void k_reg(const float4* __restrict__ p, int n4,
                                             double* __restrict__ acc) {
    int idx = blockIdx.x * blockDim.x + threadIdx.x;
    int stride = gridDim.x * blockDim.x;
    float s = 0.f;
    for (int i = idx; i < n4; i += stride) {
        float4 v = p[i];
        s += v.x * v.x + v.y * v.y + v.z * v.z + v.w * v.w;
    }
    float r = wave_reduce(s);
    __shared__ float part[4];
    int lane = threadIdx.x & 63, wv = threadIdx.x >> 6;
    if (lane == 0) part[wv] = r;
    __syncthreads();
    if (threadIdx.x == 0)
        atomicAdd(acc, (double)(part[0] + part[1] + part[2] + part[3]));
}

__global__ void k_final(const double* __restrict__ accs, float* __restrict__ out) {
    double loss = accs[0] / (double)BB + (0.01 / (2.0 * (double)BB)) * (accs[1] + accs[2]);
    out[0] = (float)loss;
}

extern "C" void kernel_launch(void* const* d_in, const int* in_sizes, int n_in,
                              void* d_out, int out_size, void* d_ws, size_t ws_size,
                              hipStream_t stream) {
    const float* rv   = (const float*)d_in[0];
    const float* rd   = (const float*)d_in[1];
    const float* proj = (const float*)d_in[2];
    const float* beta = (const float*)d_in[3];
    const int* wid    = (const int*)d_in[4];
    const int* doc    = (const int*)d_in[5];
    const int* neg    = (const int*)d_in[6];
    float* out = (float*)d_out;
    char* ws = (char*)d_ws;

    float*  normed = (float*)(ws);              // 4096*300 floats = 4,915,200 B
    float*  tpre   = (float*)(ws + 4915200);    // 4096*256 floats = 4,194,304 B
    float*  meanf  = (float*)(ws + 9109504);    // 256 floats
    float*  scalef = (float*)(ws + 9110528);    // 256 floats
    double* rowsum = (double*)(ws + 9111552);   // 256 doubles
    double* rowsq  = (double*)(ws + 9113600);   // 256 doubles
    double* accs   = (double*)(ws + 9115648);   // 3 doubles: data, rd_reg, proj_reg

    k_init<<<3, 256, 0, stream>>>(rowsum, 515);                 // rowsum+rowsq+accs contiguous
    k_gather<<<4096, 320, 0, stream>>>(rv, wid, normed);
    k_gemm<<<dim3(64, 4), 256, 0, stream>>>(proj, normed, tpre);
    k_stats1<<<64, 256, 0, stream>>>(tpre, rowsum, rowsq);
    k_stats2<<<1, 256, 0, stream>>>(rowsum, rowsq, meanf, scalef);
    k_loss<<<4096, 256, 0, stream>>>(tpre, meanf, scalef, beta, rd, doc, neg, accs);
    k_reg<<<1024, 256, 0, stream>>>((const float4*)rd, 6400000, accs + 1);
    k_reg<<<75, 256, 0, stream>>>((const float4*)proj, 19200, accs + 2);
    k_final<<<1, 1, 0, stream>>>(accs, out);
}

// Round 2
// 402.044 us; speedup vs baseline: 1.5897x; 1.5897x over previous
//
#include <hip/hip_runtime.h>
#include <math.h>

#define WE 300
#define DEp 256
#define VV 50000
#define DDim 100000
#define BB 4096
#define NGc 10

__device__ __forceinline__ float wave_reduce(float v) {
    #pragma unroll
    for (int o = 32; o > 0; o >>= 1) v += __shfl_down(v, o, 64);
    return v;
}

// log(sigmoid(x)), numerically stable
__device__ __forceinline__ float logsigf(float x) {
    return (x >= 0.f) ? -log1pf(expf(-x)) : x - log1pf(expf(x));
}

__global__ void k_init(double* p, int n) {
    int i = blockIdx.x * blockDim.x + threadIdx.x;
    if (i < n) p[i] = 0.0;
}

// Tiled 64x64 transpose: in is M x N row-major -> out is N x M row-major.
// Optionally accumulates sum(in*in) into reg_acc (each element loaded exactly once).
__global__ __launch_bounds__(256) void k_transpose(const float* __restrict__ in,
                                                   float* __restrict__ out,
                                                   int M, int N,
                                                   double* __restrict__ reg_acc) {
    __shared__ float tile[64][65];
    int n0 = blockIdx.x * 64;
    int m0 = blockIdx.y * 64;
    int tx = threadIdx.x & 63, ty = threadIdx.x >> 6;  // ty in 0..3
    float ss = 0.f;
    #pragma unroll
    for (int i = 0; i < 16; ++i) {
        int m = m0 + ty * 16 + i;
        int n = n0 + tx;
        float v = 0.f;
        if (m < M && n < N) v = in[(size_t)m * N + n];
        tile[ty * 16 + i][tx] = v;
        ss += v * v;
    }
    __syncthreads();
    #pragma unroll
    for (int i = 0; i < 16; ++i) {
        int n = n0 + ty * 16 + i;
        int m = m0 + tx;
        if (n < N && m < M) out[(size_t)n * M + m] = tile[tx][ty * 16 + i];
    }
    if (reg_acc) {
        float r = wave_reduce(ss);
        __shared__ float part[4];
        int lane = threadIdx.x & 63, wv = threadIdx.x >> 6;
        if (lane == 0) part[wv] = r;
        __syncthreads();
        if (threadIdx.x == 0)
            atomicAdd(reg_acc, (double)(part[0] + part[1] + part[2] + part[3]));
    }
}

// ---- Coalesced path (uses rvT / rdT) ----

// One block per b (320 threads, 300 active): gather g column from rvT, normalize.
__global__ __launch_bounds__(320) void k_gather2(const float* __restrict__ rvT,
                                                 const int* __restrict__ wid,
                                                 float* __restrict__ normed) {
    int b = blockIdx.x;
    int tid = threadIdx.x;
    __shared__ int ids[NGc];
    __shared__ float wpart[5];
    __shared__ float s_inv;
    if (tid < NGc) ids[tid] = wid[b * NGc + tid];
    __syncthreads();
    float g = 0.f;
    if (tid < WE) {
        #pragma unroll
        for (int ng = 0; ng < NGc; ++ng) g += rvT[(size_t)ids[ng] * WE + tid];
        g *= 0.1f;
    }
    float r = wave_reduce(g * g);
    int lane = tid & 63, wv = tid >> 6;
    if (lane == 0) wpart[wv] = r;
    __syncthreads();
    if (tid == 0) {
        float s = wpart[0] + wpart[1] + wpart[2] + wpart[3] + wpart[4];
        s_inv = 1.0f / sqrtf(s);
    }
    __syncthreads();
    if (tid < WE) normed[(size_t)b * WE + tid] = g * s_inv;
}

// One block per b: t column, dot with 1 doc + 10 neg rdT rows (coalesced), log terms.
__global__ __launch_bounds__(256) void k_loss2(const float* __restrict__ tpre,
                                               const float* __restrict__ meanf,
                                               const float* __restrict__ scalef,
                                               const float* __restrict__ beta,
                                               const float* __restrict__ rdT,
                                               const int* __restrict__ doc_ids,
                                               const int* __restrict__ neg_ids,
                                               double* __restrict__ acc) {
    int b = blockIdx.x;
    int de = threadIdx.x;
    float t = tpre[(size_t)b * DEp + de];
    float tv = (t - meanf[de]) * scalef[de] + beta[de];
    tv = fminf(1.f, fmaxf(-1.f, tv));
    __shared__ int ids[11];
    if (de == 0) ids[0] = doc_ids[b];
    if (de >= 1 && de < 11) ids[de] = neg_ids[b * NGc + de - 1];
    __syncthreads();
    float prod[11];
    #pragma unroll
    for (int j = 0; j < 11; ++j) prod[j] = tv * rdT[(size_t)ids[j] * DEp + de];
    __shared__ float part[11][4];
    int lane = de & 63, wv = de >> 6;
    #pragma unroll
    for (int j = 0; j < 11; ++j) {
        float r = wave_reduce(prod[j]);
        if (lane == 0) part[j][wv] = r;
    }
    __syncthreads();
    if (de == 0) {
        float x0 = part[0][0] + part[0][1] + part[0][2] + part[0][3];
        float total = 10.f * fminf(logsigf(x0), -1.0005003e-3f);  // Z*log(min(sig,0.999))
        #pragma unroll
        for (int j = 1; j < 11; ++j) {
            float xj = part[j][0] + part[j][1] + part[j][2] + part[j][3];
            total += fmaxf(logsigf(-xj), -4.6051702f);            // log(max(1-sig,0.01))
        }
        atomicAdd(acc, (double)(0.55f * total));                  // (Z+1)/(2Z)
    }
}

// ---- Fallback (strided) path, identical to round-1 ----

__global__ __launch_bounds__(320) void k_gather(const float* __restrict__ rv,
                                                const int* __restrict__ wid,
                                                float* __restrict__ normed) {
    int b = blockIdx.x;
    int tid = threadIdx.x;
    __shared__ int ids[NGc];
    __shared__ float wpart[5];
    __shared__ float s_inv;
    if (tid < NGc) ids[tid] = wid[b * NGc + tid];
    __syncthreads();
    float g = 0.f;
    if (tid < WE) {
        const float* row = rv + (size_t)tid * VV;
        #pragma unroll
        for (int ng = 0; ng < NGc; ++ng) g += row[ids[ng]];
        g *= 0.1f;
    }
    float r = wave_reduce(g * g);
    int lane = tid & 63, wv = tid >> 6;
    if (lane == 0) wpart[wv] = r;
    __syncthreads();
    if (tid == 0) {
        float s = wpart[0] + wpart[1] + wpart[2] + wpart[3] + wpart[4];
        s_inv = 1.0f / sqrtf(s);
    }
    __syncthreads();
    if (tid < WE) normed[(size_t)b * WE + tid] = g * s_inv;
}

__global__ __launch_bounds__(256) void k_loss(const float* __restrict__ tpre,
                                              const float* __restrict__ meanf,
                                              const float* __restrict__ scalef,
                                              const float* __restrict__ beta,
                                              const float* __restrict__ rd,
                                              const int* __restrict__ doc_ids,
                                              const int* __restrict__ neg_ids,
                                              double* __restrict__ acc) {
    int b = blockIdx.x;
    int de = threadIdx.x;
    float t = tpre[(size_t)b * DEp + de];
    float tv = (t - meanf[de]) * scalef[de] + beta[de];
    tv = fminf(1.f, fmaxf(-1.f, tv));
    const float* rdrow = rd + (size_t)de * DDim;
    __shared__ int ids[11];
    if (de == 0) ids[0] = doc_ids[b];
    if (de >= 1 && de < 11) ids[de] = neg_ids[b * NGc + de - 1];
    __syncthreads();
    float prod[11];
    #pragma unroll
    for (int j = 0; j < 11; ++j) prod[j] = tv * rdrow[ids[j]];
    __shared__ float part[11][4];
    int lane = de & 63, wv = de >> 6;
    #pragma unroll
    for (int j = 0; j < 11; ++j) {
        float r = wave_reduce(prod[j]);
        if (lane == 0) part[j][wv] = r;
    }
    __syncthreads();
    if (de == 0) {
        float x0 = part[0][0] + part[0][1] + part[0][2] + part[0][3];
        float total = 10.f * fminf(logsigf(x0), -1.0005003e-3f);
        #pragma unroll
        for (int j = 1; j < 11; ++j) {
            float xj = part[j][0] + part[j][1] + part[j][2] + part[j][3];
            total += fmaxf(logsigf(-xj), -4.6051702f);
        }
        atomicAdd(acc, (double)(0.55f * total));
    }
}

// ---- Shared middle kernels ----

// t_pre[b][de] = sum_w proj[de][w] * normed[b][w].  64x64 tiles, 4x4 micro-tile.
__global__ __launch_bounds__(256) void k_gemm(const float* __restrict__ proj,
                                              const float* __restrict__ normed,
                                              float* __restrict__ tpre) {
    __shared__ float As[64 * 33];
    __shared__ float Bs[64 * 33];
    int tid = threadIdx.x;
    int tx = tid & 15, ty = tid >> 4;
    int de0 = blockIdx.y * 64;
    int b0  = blockIdx.x * 64;
    float acc[4][4] = {};
    int f = tid & 7, r0 = tid >> 3;
    for (int kt = 0; kt < 10; ++kt) {
        int k0 = kt * 32;
        __syncthreads();
        for (int rr = r0; rr < 64; rr += 32) {
            int k = k0 + f * 4;
            float4 va = make_float4(0.f, 0.f, 0.f, 0.f);
            float4 vb = make_float4(0.f, 0.f, 0.f, 0.f);
            if (k + 3 < WE) {
                va = *(const float4*)(proj + (size_t)(de0 + rr) * WE + k);
                vb = *(const float4*)(normed + (size_t)(b0 + rr) * WE + k);
            }
            float* ap = &As[rr * 33 + f * 4];
            ap[0] = va.x; ap[1] = va.y; ap[2] = va.z; ap[3] = va.w;
            float* bp = &Bs[rr * 33 + f * 4];
            bp[0] = vb.x; bp[1] = vb.y; bp[2] = vb.z; bp[3] = vb.w;
        }
        __syncthreads();
        #pragma unroll
        for (int k = 0; k < 32; ++k) {
            float a[4], bv[4];
            #pragma unroll
            for (int i = 0; i < 4; ++i) a[i] = As[(tx * 4 + i) * 33 + k];
            #pragma unroll
            for (int j = 0; j < 4; ++j) bv[j] = Bs[(ty * 4 + j) * 33 + k];
            #pragma unroll
            for (int j = 0; j < 4; ++j)
                #pragma unroll
                for (int i = 0; i < 4; ++i) acc[j][i] += a[i] * bv[j];
        }
    }
    #pragma unroll
    for (int jb = 0; jb < 4; ++jb) {
        int b = b0 + ty * 4 + jb;
        float4 v = make_float4(acc[jb][0], acc[jb][1], acc[jb][2], acc[jb][3]);
        *(float4*)(tpre + (size_t)b * DEp + de0 + tx * 4) = v;
    }
}

__global__ __launch_bounds__(256) void k_stats1(const float* __restrict__ tpre,
                                                double* __restrict__ rowsum,
                                                double* __restrict__ rowsq) {
    int de = threadIdx.x;
    int c0 = blockIdx.x * 64;
    float s = 0.f, ss = 0.f;
    for (int i = 0; i < 64; ++i) {
        float v = tpre[(size_t)(c0 + i) * DEp + de];
        s += v; ss += v * v;
    }
    atomicAdd(&rowsum[de], (double)s);
    atomicAdd(&rowsq[de], (double)ss);
}

__global__ void k_stats2(const double* __restrict__ rowsum, const double* __restrict__ rowsq,
                         float* __restrict__ meanf, float* __restrict__ scalef) {
    int de = threadIdx.x;
    double s = rowsum[de], ss = rowsq[de];
    double mean = s / (double)BB;
    double var = (ss - s * s / (double)BB) / (double)(BB - 1);
    double stdv = sqrt(var);
    meanf[de]  = (float)mean;
    scalef[de] = (float)(1.0 / sqrt(stdv));   // reference divides by sqrt(std) = var^0.25
}

__global__ __launch_bounds__(256) void k_reg(const float4* __restrict__ p, int n4,
                                             double* __restrict__ acc) {
    int idx = blockIdx.x * blockDim.x + threadIdx.x;
    int stride = gridDim.x * blockDim.x;
    float s = 0.f;
    for (int i = idx; i < n4; i += stride) {
        float4 v = p[i];
        s += v.x * v.x + v.y * v.y + v.z * v.z + v.w * v.w;
    }
    float r = wave_reduce(s);
    __shared__ float part[4];
    int lane = threadIdx.x & 63, wv = threadIdx.x >> 6;
    if (lane == 0) part[wv] = r;
    __syncthreads();
    if (threadIdx.x == 0)
        atomicAdd(acc, (double)(part[0] + part[1] + part[2] + part[3]));
}

__global__ void k_final(const double* __restrict__ accs, float* __restrict__ out) {
    double loss = accs[0] / (double)BB + (0.01 / (2.0 * (double)BB)) * (accs[1] + accs[2]);
    out[0] = (float)loss;
}

extern "C" void kernel_launch(void* const* d_in, const int* in_sizes, int n_in,
                              void* d_out, int out_size, void* d_ws, size_t ws_size,
                              hipStream_t stream) {
    const float* rv   = (const float*)d_in[0];
    const float* rd   = (const float*)d_in[1];
    const float* proj = (const float*)d_in[2];
    const float* beta = (const float*)d_in[3];
    const int* wid    = (const int*)d_in[4];
    const int* doc    = (const int*)d_in[5];
    const int* neg    = (const int*)d_in[6];
    float* out = (float*)d_out;
    char* ws = (char*)d_ws;

    // Big-path layout: rdT (102.4 MB) at 0; rvT (60 MB) aliases it (dead before rdT written).
    const size_t off_big    = 0;
    const size_t off_normed = 102400000;
    const size_t off_tpre   = off_normed + 4915200;
    const size_t off_small  = off_tpre + 4194304;
    const size_t need = off_small + 1024 + 1024 + 2048 + 2048 + 24;

    if (ws_size >= need) {
        float*  rvT    = (float*)(ws + off_big);
        float*  rdT    = (float*)(ws + off_big);
        float*  normed = (float*)(ws + off_normed);
        float*  tpre   = (float*)(ws + off_tpre);
        float*  meanf  = (float*)(ws + off_small);
        float*  scalef = (float*)(ws + off_small + 1024);
        double* rowsum = (double*)(ws + off_small + 2048);
        double* rowsq  = (double*)(ws + off_small + 4096);
        double* accs   = (double*)(ws + off_small + 6144);

        k_init<<<3, 256, 0, stream>>>(rowsum, 515);
        k_transpose<<<dim3(782, 5), 256, 0, stream>>>(rv, rvT, WE, VV, nullptr);
        k_gather2<<<BB, 320, 0, stream>>>(rvT, wid, normed);
        k_gemm<<<dim3(64, 4), 256, 0, stream>>>(proj, normed, tpre);
        k_stats1<<<64, 256, 0, stream>>>(tpre, rowsum, rowsq);
        k_stats2<<<1, 256, 0, stream>>>(rowsum, rowsq, meanf, scalef);
        k_transpose<<<dim3(1563, 4), 256, 0, stream>>>(rd, rdT, DEp, DDim, accs + 1);
        k_loss2<<<BB, 256, 0, stream>>>(tpre, meanf, scalef, beta, rdT, doc, neg, accs);
        k_reg<<<75, 256, 0, stream>>>((const float4*)proj, 19200, accs + 2);
        k_final<<<1, 1, 0, stream>>>(accs, out);
    } else {
        // Fallback: round-1 strided path (9.2 MB workspace)
        float*  normed = (float*)(ws);
        float*  tpre   = (float*)(ws + 4915200);
        float*  meanf  = (float*)(ws + 9109504);
        float*  scalef = (float*)(ws + 9110528);
        double* rowsum = (double*)(ws + 9111552);
        double* rowsq  = (double*)(ws + 9113600);
        double* accs   = (double*)(ws + 9115648);

        k_init<<<3, 256, 0, stream>>>(rowsum, 515);
        k_gather<<<BB, 320, 0, stream>>>(rv, wid, normed);
        k_gemm<<<dim3(64, 4), 256, 0, stream>>>(proj, normed, tpre);
        k_stats1<<<64, 256, 0, stream>>>(tpre, rowsum, rowsq);
        k_stats2<<<1, 256, 0, stream>>>(rowsum, rowsq, meanf, scalef);
        k_loss<<<BB, 256, 0, stream>>>(tpre, meanf, scalef, beta, rd, doc, neg, accs);
        k_reg<<<1024, 256, 0, stream>>>((const float4*)rd, 6400000, accs + 1);
        k_reg<<<75, 256, 0, stream>>>((const float4*)proj, 19200, accs + 2);
        k_final<<<1, 1, 0, stream>>>(accs, out);
    }
}

// Round 3
// 391.039 us; speedup vs baseline: 1.6345x; 1.0281x over previous
//
#include <hip/hip_runtime.h>
#include <math.h>

#define WE 300
#define DEp 256
#define VV 50000
#define DDim 100000
#define BB 4096
#define NGc 10

__device__ __forceinline__ float wave_reduce(float v) {
    #pragma unroll
    for (int o = 32; o > 0; o >>= 1) v += __shfl_down(v, o, 64);
    return v;
}

// log(sigmoid(x)), numerically stable
__device__ __forceinline__ float logsigf(float x) {
    return (x >= 0.f) ? -log1pf(expf(-x)) : x - log1pf(expf(x));
}

__global__ void k_init(double* p, int n) {
    int i = blockIdx.x * blockDim.x + threadIdx.x;
    if (i < n) p[i] = 0.0;
}

// Tiled 64x64 transpose, float4 global loads AND stores (requires M%4==0, N%4==0).
// in: M x N row-major -> out: N x M row-major. Optionally fuses sum(in*in).
__global__ __launch_bounds__(256) void k_transpose4(const float* __restrict__ in,
                                                    float* __restrict__ out,
                                                    int M, int N,
                                                    double* __restrict__ reg_acc) {
    __shared__ float tileT[64][65];   // [n_local][m_local], stride 65: 2-way max (free)
    int n0 = blockIdx.x * 64;
    int m0 = blockIdx.y * 64;
    int t = threadIdx.x;
    int c4 = t & 15;       // 16 float4-groups across the 64-wide dimension
    int r  = t >> 4;       // 0..15
    float ss = 0.f;
    #pragma unroll
    for (int p = 0; p < 4; ++p) {
        int m = m0 + r + p * 16;
        int n = n0 + c4 * 4;
        float4 v = make_float4(0.f, 0.f, 0.f, 0.f);
        if (m < M && n < N) v = *(const float4*)(in + (size_t)m * N + n);
        ss += v.x * v.x + v.y * v.y + v.z * v.z + v.w * v.w;
        int ml = r + p * 16;
        tileT[c4 * 4 + 0][ml] = v.x;
        tileT[c4 * 4 + 1][ml] = v.y;
        tileT[c4 * 4 + 2][ml] = v.z;
        tileT[c4 * 4 + 3][ml] = v.w;
    }
    __syncthreads();
    #pragma unroll
    for (int p = 0; p < 4; ++p) {
        int n = n0 + r + p * 16;
        int m = m0 + c4 * 4;
        if (n < N && m < M) {
            int nl = r + p * 16;
            float4 v = make_float4(tileT[nl][c4 * 4 + 0], tileT[nl][c4 * 4 + 1],
                                   tileT[nl][c4 * 4 + 2], tileT[nl][c4 * 4 + 3]);
            *(float4*)(out + (size_t)n * M + m) = v;
        }
    }
    if (reg_acc) {
        float rsum = wave_reduce(ss);
        __shared__ float part[4];
        int lane = t & 63, wv = t >> 6;
        if (lane == 0) part[wv] = rsum;
        __syncthreads();
        if (t == 0)
            atomicAdd(reg_acc, (double)(part[0] + part[1] + part[2] + part[3]));
    }
}

// ---- Coalesced path (uses rvT / rdT) ----

// One block per b (320 threads, 300 active): gather g column from rvT, normalize.
__global__ __launch_bounds__(320) void k_gather2(const float* __restrict__ rvT,
                                                 const int* __restrict__ wid,
                                                 float* __restrict__ normed) {
    int b = blockIdx.x;
    int tid = threadIdx.x;
    __shared__ int ids[NGc];
    __shared__ float wpart[5];
    __shared__ float s_inv;
    if (tid < NGc) ids[tid] = wid[b * NGc + tid];
    __syncthreads();
    float g = 0.f;
    if (tid < WE) {
        #pragma unroll
        for (int ng = 0; ng < NGc; ++ng) g += rvT[(size_t)ids[ng] * WE + tid];
        g *= 0.1f;
    }
    float r = wave_reduce(g * g);
    int lane = tid & 63, wv = tid >> 6;
    if (lane == 0) wpart[wv] = r;
    __syncthreads();
    if (tid == 0) {
        float s = wpart[0] + wpart[1] + wpart[2] + wpart[3] + wpart[4];
        s_inv = 1.0f / sqrtf(s);
    }
    __syncthreads();
    if (tid < WE) normed[(size_t)b * WE + tid] = g * s_inv;
}

// One block per b: t column, dot with 1 doc + 10 neg rdT rows (coalesced), log terms.
__global__ __launch_bounds__(256) void k_loss2(const float* __restrict__ tpre,
                                               const float* __restrict__ meanf,
                                               const float* __restrict__ scalef,
                                               const float* __restrict__ beta,
                                               const float* __restrict__ rdT,
                                               const int* __restrict__ doc_ids,
                                               const int* __restrict__ neg_ids,
                                               double* __restrict__ acc) {
    int b = blockIdx.x;
    int de = threadIdx.x;
    float t = tpre[(size_t)b * DEp + de];
    float tv = (t - meanf[de]) * scalef[de] + beta[de];
    tv = fminf(1.f, fmaxf(-1.f, tv));
    __shared__ int ids[11];
    if (de == 0) ids[0] = doc_ids[b];
    if (de >= 1 && de < 11) ids[de] = neg_ids[b * NGc + de - 1];
    __syncthreads();
    float prod[11];
    #pragma unroll
    for (int j = 0; j < 11; ++j) prod[j] = tv * rdT[(size_t)ids[j] * DEp + de];
    __shared__ float part[11][4];
    int lane = de & 63, wv = de >> 6;
    #pragma unroll
    for (int j = 0; j < 11; ++j) {
        float r = wave_reduce(prod[j]);
        if (lane == 0) part[j][wv] = r;
    }
    __syncthreads();
    if (de == 0) {
        float x0 = part[0][0] + part[0][1] + part[0][2] + part[0][3];
        float total = 10.f * fminf(logsigf(x0), -1.0005003e-3f);  // Z*log(min(sig,0.999))
        #pragma unroll
        for (int j = 1; j < 11; ++j) {
            float xj = part[j][0] + part[j][1] + part[j][2] + part[j][3];
            total += fmaxf(logsigf(-xj), -4.6051702f);            // log(max(1-sig,0.01))
        }
        atomicAdd(acc, (double)(0.55f * total));                  // (Z+1)/(2Z)
    }
}

// ---- Fallback (strided) path ----

__global__ __launch_bounds__(320) void k_gather(const float* __restrict__ rv,
                                                const int* __restrict__ wid,
                                                float* __restrict__ normed) {
    int b = blockIdx.x;
    int tid = threadIdx.x;
    __shared__ int ids[NGc];
    __shared__ float wpart[5];
    __shared__ float s_inv;
    if (tid < NGc) ids[tid] = wid[b * NGc + tid];
    __syncthreads();
    float g = 0.f;
    if (tid < WE) {
        const float* row = rv + (size_t)tid * VV;
        #pragma unroll
        for (int ng = 0; ng < NGc; ++ng) g += row[ids[ng]];
        g *= 0.1f;
    }
    float r = wave_reduce(g * g);
    int lane = tid & 63, wv = tid >> 6;
    if (lane == 0) wpart[wv] = r;
    __syncthreads();
    if (tid == 0) {
        float s = wpart[0] + wpart[1] + wpart[2] + wpart[3] + wpart[4];
        s_inv = 1.0f / sqrtf(s);
    }
    __syncthreads();
    if (tid < WE) normed[(size_t)b * WE + tid] = g * s_inv;
}

__global__ __launch_bounds__(256) void k_loss(const float* __restrict__ tpre,
                                              const float* __restrict__ meanf,
                                              const float* __restrict__ scalef,
                                              const float* __restrict__ beta,
                                              const float* __restrict__ rd,
                                              const int* __restrict__ doc_ids,
                                              const int* __restrict__ neg_ids,
                                              double* __restrict__ acc) {
    int b = blockIdx.x;
    int de = threadIdx.x;
    float t = tpre[(size_t)b * DEp + de];
    float tv = (t - meanf[de]) * scalef[de] + beta[de];
    tv = fminf(1.f, fmaxf(-1.f, tv));
    const float* rdrow = rd + (size_t)de * DDim;
    __shared__ int ids[11];
    if (de == 0) ids[0] = doc_ids[b];
    if (de >= 1 && de < 11) ids[de] = neg_ids[b * NGc + de - 1];
    __syncthreads();
    float prod[11];
    #pragma unroll
    for (int j = 0; j < 11; ++j) prod[j] = tv * rdrow[ids[j]];
    __shared__ float part[11][4];
    int lane = de & 63, wv = de >> 6;
    #pragma unroll
    for (int j = 0; j < 11; ++j) {
        float r = wave_reduce(prod[j]);
        if (lane == 0) part[j][wv] = r;
    }
    __syncthreads();
    if (de == 0) {
        float x0 = part[0][0] + part[0][1] + part[0][2] + part[0][3];
        float total = 10.f * fminf(logsigf(x0), -1.0005003e-3f);
        #pragma unroll
        for (int j = 1; j < 11; ++j) {
            float xj = part[j][0] + part[j][1] + part[j][2] + part[j][3];
            total += fmaxf(logsigf(-xj), -4.6051702f);
        }
        atomicAdd(acc, (double)(0.55f * total));
    }
}

// ---- Shared middle kernels ----

// t_pre[b][de] = sum_w proj[de][w] * normed[b][w].  64x64 tiles, 4x4 micro-tile.
__global__ __launch_bounds__(256) void k_gemm(const float* __restrict__ proj,
                                              const float* __restrict__ normed,
                                              float* __restrict__ tpre) {
    __shared__ float As[64 * 33];
    __shared__ float Bs[64 * 33];
    int tid = threadIdx.x;
    int tx = tid & 15, ty = tid >> 4;
    int de0 = blockIdx.y * 64;
    int b0  = blockIdx.x * 64;
    float acc[4][4] = {};
    int f = tid & 7, r0 = tid >> 3;
    for (int kt = 0; kt < 10; ++kt) {
        int k0 = kt * 32;
        __syncthreads();
        for (int rr = r0; rr < 64; rr += 32) {
            int k = k0 + f * 4;
            float4 va = make_float4(0.f, 0.f, 0.f, 0.f);
            float4 vb = make_float4(0.f, 0.f, 0.f, 0.f);
            if (k + 3 < WE) {
                va = *(const float4*)(proj + (size_t)(de0 + rr) * WE + k);
                vb = *(const float4*)(normed + (size_t)(b0 + rr) * WE + k);
            }
            float* ap = &As[rr * 33 + f * 4];
            ap[0] = va.x; ap[1] = va.y; ap[2] = va.z; ap[3] = va.w;
            float* bp = &Bs[rr * 33 + f * 4];
            bp[0] = vb.x; bp[1] = vb.y; bp[2] = vb.z; bp[3] = vb.w;
        }
        __syncthreads();
        #pragma unroll
        for (int k = 0; k < 32; ++k) {
            float a[4], bv[4];
            #pragma unroll
            for (int i = 0; i < 4; ++i) a[i] = As[(tx * 4 + i) * 33 + k];
            #pragma unroll
            for (int j = 0; j < 4; ++j) bv[j] = Bs[(ty * 4 + j) * 33 + k];
            #pragma unroll
            for (int j = 0; j < 4; ++j)
                #pragma unroll
                for (int i = 0; i < 4; ++i) acc[j][i] += a[i] * bv[j];
        }
    }
    #pragma unroll
    for (int jb = 0; jb < 4; ++jb) {
        int b = b0 + ty * 4 + jb;
        float4 v = make_float4(acc[jb][0], acc[jb][1], acc[jb][2], acc[jb][3]);
        *(float4*)(tpre + (size_t)b * DEp + de0 + tx * 4) = v;
    }
}

__global__ __launch_bounds__(256) void k_stats1(const float* __restrict__ tpre,
                                                double* __restrict__ rowsum,
                                                double* __restrict__ rowsq) {
    int de = threadIdx.x;
    int c0 = blockIdx.x * 64;
    float s = 0.f, ss = 0.f;
    for (int i = 0; i < 64; ++i) {
        float v = tpre[(size_t)(c0 + i) * DEp + de];
        s += v; ss += v * v;
    }
    atomicAdd(&rowsum[de], (double)s);
    atomicAdd(&rowsq[de], (double)ss);
}

__global__ void k_stats2(const double* __restrict__ rowsum, const double* __restrict__ rowsq,
                         float* __restrict__ meanf, float* __restrict__ scalef) {
    int de = threadIdx.x;
    double s = rowsum[de], ss = rowsq[de];
    double mean = s / (double)BB;
    double var = (ss - s * s / (double)BB) / (double)(BB - 1);
    double stdv = sqrt(var);
    meanf[de]  = (float)mean;
    scalef[de] = (float)(1.0 / sqrt(stdv));   // reference divides by sqrt(std) = var^0.25
}

__global__ __launch_bounds__(256) void k_reg(const float4* __restrict__ p, int n4,
                                             double* __restrict__ acc) {
    int idx = blockIdx.x * blockDim.x + threadIdx.x;
    int stride = gridDim.x * blockDim.x;
    float s = 0.f;
    for (int i = idx; i < n4; i += stride) {
        float4 v = p[i];
        s += v.x * v.x + v.y * v.y + v.z * v.z + v.w * v.w;
    }
    float r = wave_reduce(s);
    __shared__ float part[4];
    int lane = threadIdx.x & 63, wv = threadIdx.x >> 6;
    if (lane == 0) part[wv] = r;
    __syncthreads();
    if (threadIdx.x == 0)
        atomicAdd(acc, (double)(part[0] + part[1] + part[2] + part[3]));
}

__global__ void k_final(const double* __restrict__ accs, float* __restrict__ out) {
    double loss = accs[0] / (double)BB + (0.01 / (2.0 * (double)BB)) * (accs[1] + accs[2]);
    out[0] = (float)loss;
}

extern "C" void kernel_launch(void* const* d_in, const int* in_sizes, int n_in,
                              void* d_out, int out_size, void* d_ws, size_t ws_size,
                              hipStream_t stream) {
    const float* rv   = (const float*)d_in[0];
    const float* rd   = (const float*)d_in[1];
    const float* proj = (const float*)d_in[2];
    const float* beta = (const float*)d_in[3];
    const int* wid    = (const int*)d_in[4];
    const int* doc    = (const int*)d_in[5];
    const int* neg    = (const int*)d_in[6];
    float* out = (float*)d_out;
    char* ws = (char*)d_ws;

    // Big-path layout: rdT (102.4 MB) at 0; rvT (60 MB) aliases it (dead before rdT written).
    const size_t off_big    = 0;
    const size_t off_normed = 102400000;
    const size_t off_tpre   = off_normed + 4915200;
    const size_t off_small  = off_tpre + 4194304;
    const size_t need = off_small + 1024 + 1024 + 2048 + 2048 + 24;

    if (ws_size >= need) {
        float*  rvT    = (float*)(ws + off_big);
        float*  rdT    = (float*)(ws + off_big);
        float*  normed = (float*)(ws + off_normed);
        float*  tpre   = (float*)(ws + off_tpre);
        float*  meanf  = (float*)(ws + off_small);
        float*  scalef = (float*)(ws + off_small + 1024);
        double* rowsum = (double*)(ws + off_small + 2048);
        double* rowsq  = (double*)(ws + off_small + 4096);
        double* accs   = (double*)(ws + off_small + 6144);

        k_init<<<3, 256, 0, stream>>>(rowsum, 515);
        k_transpose4<<<dim3(782, 5), 256, 0, stream>>>(rv, rvT, WE, VV, nullptr);
        k_gather2<<<BB, 320, 0, stream>>>(rvT, wid, normed);
        k_gemm<<<dim3(64, 4), 256, 0, stream>>>(proj, normed, tpre);
        k_stats1<<<64, 256, 0, stream>>>(tpre, rowsum, rowsq);
        k_stats2<<<1, 256, 0, stream>>>(rowsum, rowsq, meanf, scalef);
        k_transpose4<<<dim3(1563, 4), 256, 0, stream>>>(rd, rdT, DEp, DDim, accs + 1);
        k_loss2<<<BB, 256, 0, stream>>>(tpre, meanf, scalef, beta, rdT, doc, neg, accs);
        k_reg<<<75, 256, 0, stream>>>((const float4*)proj, 19200, accs + 2);
        k_final<<<1, 1, 0, stream>>>(accs, out);
    } else {
        // Fallback: strided path (9.2 MB workspace)
        float*  normed = (float*)(ws);
        float*  tpre   = (float*)(ws + 4915200);
        float*  meanf  = (float*)(ws + 9109504);
        float*  scalef = (float*)(ws + 9110528);
        double* rowsum = (double*)(ws + 9111552);
        double* rowsq  = (double*)(ws + 9113600);
        double* accs   = (double*)(ws + 9115648);

        k_init<<<3, 256, 0, stream>>>(rowsum, 515);
        k_gather<<<BB, 320, 0, stream>>>(rv, wid, normed);
        k_gemm<<<dim3(64, 4), 256, 0, stream>>>(proj, normed, tpre);
        k_stats1<<<64, 256, 0, stream>>>(tpre, rowsum, rowsq);
        k_stats2<<<1, 256, 0, stream>>>(rowsum, rowsq, meanf, scalef);
        k_loss<<<BB, 256, 0, stream>>>(tpre, meanf, scalef, beta, rd, doc, neg, accs);
        k_reg<<<1024, 256, 0, stream>>>((const float4*)rd, 6400000, accs + 1);
        k_reg<<<75, 256, 0, stream>>>((const float4*)proj, 19200, accs + 2);
        k_final<<<1, 1, 0, stream>>>(accs, out);
    }
}